// Round 2
// baseline (944.023 us; speedup 1.0000x reference)
//
#include <hip/hip_runtime.h>
#include <hip/hip_bf16.h>
#include <stdint.h>

typedef __attribute__((ext_vector_type(8))) short short8;
typedef __attribute__((ext_vector_type(4))) float floatx4;
typedef uint32_t u32;

#define N_NODES 100000
#define N_EDGES 1600000
#define ALPHA_SLOPE 0.2f
#define EPS_F 1e-16f

static __device__ __forceinline__ float bf2f(ushort h) {
    u32 u = ((u32)h) << 16;
    return __builtin_bit_cast(float, u);
}
static __device__ __forceinline__ ushort f2bf(float f) {
    u32 u = __builtin_bit_cast(u32, f);
    u32 r = (u + 0x7fffu + ((u >> 16) & 1u)) >> 16;
    return (ushort)r;
}

// ---------------- convert features f32 -> bf16 (vectorized) ----------------
__global__ __launch_bounds__(256) void conv_feat(
    const float* __restrict__ in, ushort* __restrict__ out, int n4)
{
    int i = blockIdx.x * 256 + threadIdx.x;
    if (i < n4) {
        float4 v = ((const float4*)in)[i];
        ushort4 o;
        o.x = f2bf(v.x); o.y = f2bf(v.y); o.z = f2bf(v.z); o.w = f2bf(v.w);
        ((ushort4*)out)[i] = o;
    }
}

// ---------------- pretranspose W / W_out (f32) into k-packed bf16 B layout ----------------
// Bp[((k>>3)*NP + n)*8 + (k&7)] = bf16(B[k][n]); Bp2 zero-padded to 128 cols.
__global__ __launch_bounds__(256) void pretranspose(
    const float* __restrict__ W, const float* __restrict__ Wout,
    ushort* __restrict__ Bp1, ushort* __restrict__ Bp2)
{
    int idx = blockIdx.x * 256 + threadIdx.x;
    if (idx < 256 * 512) {  // Bp1: K=256, N=512
        int k = idx >> 9, n = idx & 511;
        int head = n >> 6, c = n & 63;
        Bp1[((size_t)(k >> 3) * 512 + n) * 8 + (k & 7)] = f2bf(W[head * 16384 + k * 64 + c]);
    }
    if (idx < 512 * 128) {  // Bp2: K=512, N=97 padded to 128
        int k = idx >> 7, n = idx & 127;
        ushort v = (n < 97) ? f2bf(Wout[k * 97 + n]) : (ushort)0;
        Bp2[((size_t)(k >> 3) * 128 + n) * 8 + (k & 7)] = v;
    }
}

// ---------------- MFMA GEMM: C[M,NP] = A[M,K] @ B[K,NP] (bf16 in/out, f32 acc) ----------------
__global__ __launch_bounds__(256) void gemm_mfma(
    const ushort* __restrict__ A, const ushort* __restrict__ Bp,
    ushort* __restrict__ C, int M, int K, int NP)
{
    __shared__ __align__(16) ushort Ald[4 * 128 * 8];  // [kq][r][j], 8 KB
    const int tid = threadIdx.x;
    const int lane = tid & 63;
    const int wave = tid >> 6;
    const int wr = wave >> 1, wc = wave & 1;
    const int row0 = blockIdx.x * 128;
    const int col0 = blockIdx.y * 128;
    const int quad = lane >> 4;
    const int l16 = lane & 15;

    floatx4 acc[4][4] = {};

    for (int k0 = 0; k0 < K; k0 += 32) {
        __syncthreads();
#pragma unroll
        for (int i = 0; i < 2; ++i) {
            int q = i * 256 + tid;          // 512 chunks of 16B
            int r = q >> 2, kq = q & 3;
            int row = row0 + r;
            if (row >= M) row = M - 1;      // clamp: garbage rows never stored
            const uint4* src = (const uint4*)(A + (size_t)row * K + k0 + kq * 8);
            *(uint4*)(&Ald[((kq * 128 + r) * 8)]) = *src;
        }
        __syncthreads();

        short8 bfrag[4];
        int kqg = (k0 >> 3) + quad;
#pragma unroll
        for (int nt = 0; nt < 4; ++nt) {
            int col = col0 + wc * 64 + nt * 16 + l16;
            bfrag[nt] = *(const short8*)(Bp + ((size_t)kqg * NP + col) * 8);
        }
#pragma unroll
        for (int mt = 0; mt < 4; ++mt) {
            int r = wr * 64 + mt * 16 + l16;
            short8 afrag = *(const short8*)(&Ald[(quad * 128 + r) * 8]);
#pragma unroll
            for (int nt = 0; nt < 4; ++nt) {
                acc[mt][nt] = __builtin_amdgcn_mfma_f32_16x16x32_bf16(afrag, bfrag[nt], acc[mt][nt], 0, 0, 0);
            }
        }
    }

#pragma unroll
    for (int mt = 0; mt < 4; ++mt) {
#pragma unroll
        for (int rr = 0; rr < 4; ++rr) {
            int row = row0 + wr * 64 + mt * 16 + quad * 4 + rr;
            if (row < M) {
#pragma unroll
                for (int nt = 0; nt < 4; ++nt) {
                    int col = col0 + wc * 64 + nt * 16 + l16;
                    C[(size_t)row * NP + col] = f2bf(acc[mt][nt][rr]);
                }
            }
        }
    }
}

// ---------------- per-(node,head) attention scores, layer 1 ----------------
__global__ __launch_bounds__(256) void sk1(
    const ushort* __restrict__ h_all, const float* __restrict__ a,
    float* __restrict__ ssrc, float* __restrict__ sdst, int N)
{
    int w = blockIdx.x * 4 + (threadIdx.x >> 6);
    int i = w >> 3, k = w & 7, l = threadIdx.x & 63;
    if (i >= N) return;
    float v = bf2f(h_all[(size_t)i * 512 + k * 64 + l]);
    float s1 = v * a[k * 128 + l];
    float s2 = v * a[k * 128 + 64 + l];
#pragma unroll
    for (int o = 32; o; o >>= 1) { s1 += __shfl_xor(s1, o); s2 += __shfl_xor(s2, o); }
    if (l == 0) { ssrc[i * 8 + k] = s1; sdst[i * 8 + k] = s2; }
}

// ---------------- CSR build ----------------
__global__ __launch_bounds__(256) void hist(const int* __restrict__ ei, int* __restrict__ cnt, int E) {
    int e = blockIdx.x * 256 + threadIdx.x;
    if (e < E) atomicAdd(&cnt[ei[e]], 1);
}

__global__ __launch_bounds__(256) void scan_partial(const int* __restrict__ cnt, int* __restrict__ bsum, int N) {
    int idx = blockIdx.x * 256 + threadIdx.x;
    int v = (idx < N) ? cnt[idx] : 0;
#pragma unroll
    for (int o = 32; o; o >>= 1) v += __shfl_xor(v, o);
    __shared__ int ws[4];
    if ((threadIdx.x & 63) == 0) ws[threadIdx.x >> 6] = v;
    __syncthreads();
    if (threadIdx.x == 0) bsum[blockIdx.x] = ws[0] + ws[1] + ws[2] + ws[3];
}

__global__ __launch_bounds__(512) void scan_block(int* __restrict__ bsum, int nb) {
    __shared__ int s[512];
    int t = threadIdx.x;
    int v = (t < nb) ? bsum[t] : 0;
    s[t] = v;
    __syncthreads();
    for (int o = 1; o < 512; o <<= 1) {
        int u = (t >= o) ? s[t - o] : 0;
        __syncthreads();
        s[t] += u;
        __syncthreads();
    }
    if (t < nb) bsum[t] = s[t] - v;  // exclusive
}

__global__ __launch_bounds__(256) void scan_final(
    const int* __restrict__ cnt, const int* __restrict__ bsum,
    int* __restrict__ row_ptr, int N, int E)
{
    int b = blockIdx.x, t = threadIdx.x;
    int idx = b * 256 + t;
    int v = (idx < N) ? cnt[idx] : 0;
    __shared__ int s[256];
    s[t] = v;
    __syncthreads();
    for (int o = 1; o < 256; o <<= 1) {
        int u = (t >= o) ? s[t - o] : 0;
        __syncthreads();
        s[t] += u;
        __syncthreads();
    }
    if (idx < N) row_ptr[idx] = bsum[b] + s[t] - v;
    if (idx == 0) row_ptr[N] = E;
}

__global__ __launch_bounds__(256) void fill_csr(
    const int* __restrict__ ei, const int* __restrict__ row_ptr,
    int* __restrict__ cur, int* __restrict__ col_idx, int E)
{
    int e = blockIdx.x * 256 + threadIdx.x;
    if (e < E) {
        int s = ei[e];
        int d = ei[E + e];
        int p = atomicAdd(&cur[s], 1);
        col_idx[row_ptr[s] + p] = d;
    }
}

// ---------------- layer-1 edge aggregation + normalize + ELU ----------------
__global__ __launch_bounds__(256) void ea1(
    const int* __restrict__ row_ptr, const int* __restrict__ col_idx,
    const ushort* __restrict__ h_all, const float* __restrict__ ssrc,
    const float* __restrict__ sdst, ushort* __restrict__ x1)
{
    int i = blockIdx.x;
    int t = threadIdx.x;
    int hk = t >> 5;
    int start = row_ptr[i], end = row_ptr[i + 1];
    float si = ssrc[i * 8 + hk];
    float accx = 0.f, accy = 0.f, re = 0.f;
    __shared__ int dl[256];
    for (int j0 = start; j0 < end; j0 += 256) {
        int c = end - j0; if (c > 256) c = 256;
        __syncthreads();
        if (t < c) dl[t] = col_idx[j0 + t];
        __syncthreads();
        for (int jj = 0; jj < c; ++jj) {
            int d = dl[jj];
            float s = si + sdst[d * 8 + hk];
            float lr = s > 0.f ? s : ALPHA_SLOPE * s;
            float e = __expf(-lr);
            u32 hv = *(const u32*)(h_all + (size_t)d * 512 + 2 * t);
            accx = fmaf(e, bf2f((ushort)(hv & 0xffffu)), accx);
            accy = fmaf(e, bf2f((ushort)(hv >> 16)), accy);
            re += e;
        }
    }
    float inv = 1.f / (re + EPS_F);
    float px = accx * inv, py = accy * inv;
    px = px > 0.f ? px : expm1f(px);
    py = py > 0.f ? py : expm1f(py);
    u32 o = (u32)f2bf(px) | ((u32)f2bf(py) << 16);
    *(u32*)(x1 + (size_t)i * 512 + 2 * t) = o;
}

// ---------------- layer-2 scores ----------------
__global__ __launch_bounds__(256) void sk2(
    const ushort* __restrict__ h2p, const float* __restrict__ aout,
    float* __restrict__ s2src, float* __restrict__ s2dst, int N)
{
    int w = blockIdx.x * 4 + (threadIdx.x >> 6);
    if (w >= N) return;
    int l = threadIdx.x & 63;
    float s1 = 0.f, s2 = 0.f;
    for (int c = l; c < 97; c += 64) {
        float v = bf2f(h2p[(size_t)w * 128 + c]);
        s1 = fmaf(v, aout[c], s1);
        s2 = fmaf(v, aout[97 + c], s2);
    }
#pragma unroll
    for (int o = 32; o; o >>= 1) { s1 += __shfl_xor(s1, o); s2 += __shfl_xor(s2, o); }
    if (l == 0) { s2src[w] = s1; s2dst[w] = s2; }
}

// ---------------- layer-2 aggregation + ELU + log_softmax (f32 out) ----------------
__global__ __launch_bounds__(128) void ea2(
    const int* __restrict__ row_ptr, const int* __restrict__ col_idx,
    const ushort* __restrict__ h2p, const float* __restrict__ s2src,
    const float* __restrict__ s2dst, float* __restrict__ out)
{
    int i = blockIdx.x;
    int t = threadIdx.x;
    int start = row_ptr[i], end = row_ptr[i + 1];
    float si = s2src[i];
    float acc = 0.f, re = 0.f;
    __shared__ int dl[128];
    for (int j0 = start; j0 < end; j0 += 128) {
        int c = end - j0; if (c > 128) c = 128;
        __syncthreads();
        if (t < c) dl[t] = col_idx[j0 + t];
        __syncthreads();
        for (int jj = 0; jj < c; ++jj) {
            int d = dl[jj];
            float s = si + s2dst[d];
            float lr = s > 0.f ? s : ALPHA_SLOPE * s;
            float e = __expf(-lr);
            float hv = bf2f(h2p[(size_t)d * 128 + t]);  // cols>=97 are exact 0
            acc = fmaf(e, hv, acc);
            re += e;
        }
    }
    float v = acc / (re + EPS_F);
    v = v > 0.f ? v : expm1f(v);
    bool valid = t < 97;
    float m = valid ? v : -1e30f;
#pragma unroll
    for (int o = 32; o; o >>= 1) m = fmaxf(m, __shfl_xor(m, o));
    __shared__ float smax[2], ssum[2];
    if ((t & 63) == 0) smax[t >> 6] = m;
    __syncthreads();
    m = fmaxf(smax[0], smax[1]);
    float ex = valid ? __expf(v - m) : 0.f;
#pragma unroll
    for (int o = 32; o; o >>= 1) ex += __shfl_xor(ex, o);
    if ((t & 63) == 0) ssum[t >> 6] = ex;
    __syncthreads();
    float tot = ssum[0] + ssum[1];
    if (valid) out[(size_t)i * 97 + t] = v - m - logf(tot);
}

extern "C" void kernel_launch(void* const* d_in, const int* in_sizes, int n_in,
                              void* d_out, int out_size, void* d_ws, size_t ws_size,
                              hipStream_t stream)
{
    const float* feat = (const float*)d_in[0];   // [N,256] f32
    const float* W    = (const float*)d_in[1];   // [8,256,64] f32
    const float* a    = (const float*)d_in[2];   // [8,128] f32
    const float* Wout = (const float*)d_in[3];   // [512,97] f32
    const float* aout = (const float*)d_in[4];   // [194] f32
    const int*   ei   = (const int*)d_in[5];     // [2,E] int32
    float* out = (float*)d_out;                  // [N,97] f32

    const int N = N_NODES, E = N_EDGES;
    const int NB = (N + 255) / 256;  // 391

    // explicit workspace layout with lifetime aliasing (peak ~258 MiB)
    char* base = (char*)d_ws;
    ushort* h_all = (ushort*)(base);                         // 102,400,000 B  [gemm1 .. ea1]
    ushort* x1    = (ushort*)(base + 102400000);             // 102,400,000 B  [ea1 .. gemm2]
    ushort* featb = (ushort*)(base + 204800000);             // 51,200,000 B   [conv .. gemm1]
    ushort* h2p   = (ushort*)(base + 204800000);             // 25,600,000 B   [gemm2 .. ea2]  (aliases featb)
    char* tail = base + 256000000;
    float* ssrc    = (float*)(tail + 0);                     // 3,200,000
    float* sdst    = (float*)(tail + 3200000);               // 3,200,000
    float* s2src   = (float*)(tail + 6400000);               // 400,000
    float* s2dst   = (float*)(tail + 6800000);               // 400,000
    int*   row_ptr = (int*)(tail + 7200000);                 // 400,128
    int*   cnt     = (int*)(tail + 7600128);                 // 400,000
    int*   col_idx = (int*)(tail + 8000128);                 // 6,400,000
    int*   bsum    = (int*)(tail + 14400128);                // 1,792
    ushort* Bp1    = (ushort*)(tail + 14401920);             // 262,144
    ushort* Bp2    = (ushort*)(tail + 14664064);             // 131,072

    hipMemsetAsync(cnt, 0, (size_t)N * 4, stream);
    conv_feat<<<(N * 256 / 4 + 255) / 256, 256, 0, stream>>>(feat, featb, N * 256 / 4);
    pretranspose<<<512, 256, 0, stream>>>(W, Wout, Bp1, Bp2);

    // layer 1 projections + scores
    gemm_mfma<<<dim3(782, 4), 256, 0, stream>>>(featb, Bp1, h_all, N, 256, 512);
    sk1<<<(N * 8 + 3) / 4, 256, 0, stream>>>(h_all, a, ssrc, sdst, N);

    // CSR
    hist<<<(E + 255) / 256, 256, 0, stream>>>(ei, cnt, E);
    scan_partial<<<NB, 256, 0, stream>>>(cnt, bsum, N);
    scan_block<<<1, 512, 0, stream>>>(bsum, NB);
    scan_final<<<NB, 256, 0, stream>>>(cnt, bsum, row_ptr, N, E);
    hipMemsetAsync(cnt, 0, (size_t)N * 4, stream);
    fill_csr<<<(E + 255) / 256, 256, 0, stream>>>(ei, row_ptr, cnt, col_idx, E);

    // layer 1 aggregation
    ea1<<<N, 256, 0, stream>>>(row_ptr, col_idx, h_all, ssrc, sdst, x1);

    // layer 2
    gemm_mfma<<<dim3(782, 1), 256, 0, stream>>>(x1, Bp2, h2p, N, 512, 128);
    sk2<<<(N + 3) / 4, 256, 0, stream>>>(h2p, aout, s2src, s2dst, N);
    ea2<<<N, 128, 0, stream>>>(row_ptr, col_idx, h2p, s2src, s2dst, out);
}